// Round 9
// baseline (370.361 us; speedup 1.0000x reference)
//
#include <hip/hip_runtime.h>
#include <hip/hip_bf16.h>
#include <cstdint>
#include <cstddef>

// Problem constants
#define NTOK 49
#define DIM 384
#define KDIM 384
#define HEADS 12
#define HD 32
#define BATCH 2048
#define MROWS (BATCH * NTOK)   // 100352 = 784 * 128

typedef unsigned short u16;
typedef __bf16 bf16x8 __attribute__((ext_vector_type(8)));
typedef unsigned short u16x8 __attribute__((ext_vector_type(8)));
typedef float f32x4 __attribute__((ext_vector_type(4)));

__device__ __forceinline__ u16 f2b(float f) {
  union { float f; unsigned u; } v; v.f = f;
  unsigned r = v.u + 0x7fffu + ((v.u >> 16) & 1u);   // RNE bf16
  return (u16)(r >> 16);
}

__device__ __forceinline__ bf16x8 ld_bf8(const u16* p) {
  u16x8 u = *(const u16x8*)p;
  return __builtin_bit_cast(bf16x8, u);
}

__device__ __forceinline__ void gload_lds16(const void* g, void* l) {
  __builtin_amdgcn_global_load_lds(
      (const __attribute__((address_space(1))) unsigned*)g,
      (__attribute__((address_space(3))) unsigned*)l, 16, 0, 0);
}

// ---------------- prep: x/w casts + fused bias+mask table, one launch -------
__global__ __launch_bounds__(256) void k_prep(const float* __restrict__ x,
                                              u16* __restrict__ xb,
                                              const float* __restrict__ qkv_w,
                                              u16* __restrict__ wqkvb,
                                              const float* __restrict__ proj_w,
                                              u16* __restrict__ wprojb,
                                              const float* __restrict__ bias_table,
                                              const float* __restrict__ mask,
                                              const int* __restrict__ rel_idx,
                                              float* __restrict__ rpbm) {
  int blk = blockIdx.x;
  if (blk < 38208) {
    const float* in;
    u16* out;
    int i;
    if (blk < 37632) {
      in = x; out = xb; i = blk * 256 + threadIdx.x;
    } else if (blk < 38064) {
      in = qkv_w; out = wqkvb; i = (blk - 37632) * 256 + threadIdx.x;
    } else {
      in = proj_w; out = wprojb; i = (blk - 38064) * 256 + threadIdx.x;
    }
    float4 v = ((const float4*)in)[i];
    ushort4 o;
    o.x = f2b(v.x); o.y = f2b(v.y); o.z = f2b(v.z); o.w = f2b(v.w);
    ((ushort4*)out)[i] = o;
  } else {
    int idx = (blk - 38208) * 256 + threadIdx.x;   // 12*64*4096 entries
    int r  = idx & 3;
    int l  = (idx >> 2) & 63;
    int ni = (idx >> 8) & 3;
    int mi = (idx >> 10) & 3;
    int w  = (idx >> 12) & 63;
    int h  = idx >> 18;
    int row = mi * 16 + (l >> 4) * 4 + r;
    int col = ni * 16 + (l & 15);
    float v = -1e30f;
    if (row < NTOK && col < NTOK)
      v = bias_table[rel_idx[row * NTOK + col] * HEADS + h] +
          mask[(w * NTOK + row) * NTOK + col];
    rpbm[idx] = v;
  }
}

// ------- QKV GEMM: 4-buffer, ONE barrier per K-step, reg-prefetched frags ---
// Iter t: STAGE(t+3 -> buf (t+3)%4) ; MFMA on regs(tile t) ; vmcnt(N) ;
//         s_barrier ; ds_read(tile t+1 -> regs).
// WAR safety: stage at iter t+1 targets buf t%4; every wave's tile-t ds_reads
// were consumed by its MFMAs BEFORE barrier(t), so one barrier suffices.
// T2 swizzle (same involution as round 7): linear LDS dest, pre-swizzled
// global source seg = (lane&3)^((lane>>3)&3); read seg gsw = g^((c>>1)&3).
template <int NCOLS, int NTN, int GD8>
__global__ __launch_bounds__(256) void k_gemm4(const u16* __restrict__ A,
                                               const u16* __restrict__ B,
                                               const float* __restrict__ bias,
                                               u16* __restrict__ C) {
  __shared__ u16 sh[32768];   // 64KB: 4 x (As 8KB + Bs 8KB); epilogue reuses 32KB
  int bid = blockIdx.x;
  int tile = (bid & 7) * GD8 + (bid >> 3);   // XCD-contiguous (grid % 8 == 0)
  int mt = tile / NTN, nt = tile - mt * NTN;
  long m0 = (long)mt * 128;
  int n0 = nt * 128;
  int tid = threadIdx.x;
  int lane = tid & 63, wid = tid >> 6;
  int wr = (wid >> 1) * 64, wc = (wid & 1) * 64;
  int c = lane & 15, g = lane >> 4;
  int gsw = (g ^ ((c >> 1) & 3)) * 8;        // swizzled read segment (u16 units)

  int srow = wid * 16 + (lane >> 2);
  int scol = ((lane & 3) ^ ((lane >> 3) & 3)) * 8;   // pre-swizzled global seg
  const u16* gA = A + (m0 + srow) * (long)KDIM + scol;
  const u16* gB = B + (long)(n0 + srow) * KDIM + scol;
  int lrow = srow, lseg = (lane & 3) * 8;            // linear LDS dest

  f32x4 acc[4][4] = {};
  bf16x8 af[4], bfr[4];

#define STAGE4(BUF, KT)                                                        \
  {                                                                            \
    u16* As_ = sh + (BUF) * 8192;                                              \
    u16* Bs_ = As_ + 4096;                                                     \
    gload_lds16(gA + (KT), &As_[lrow * 32 + lseg]);                            \
    gload_lds16(gA + (KT) + 64L * KDIM, &As_[(lrow + 64) * 32 + lseg]);        \
    gload_lds16(gB + (KT), &Bs_[lrow * 32 + lseg]);                            \
    gload_lds16(gB + (KT) + 64L * KDIM, &Bs_[(lrow + 64) * 32 + lseg]);        \
  }

#define FRAGREAD(BUF)                                                          \
  {                                                                            \
    const u16* As = sh + (BUF) * 8192;                                         \
    const u16* Bs = As + 4096;                                                 \
    _Pragma("unroll") for (int i = 0; i < 4; ++i) {                            \
      af[i]  = ld_bf8(&As[(wr + i * 16 + c) * 32 + gsw]);                      \
      bfr[i] = ld_bf8(&Bs[(wc + i * 16 + c) * 32 + gsw]);                      \
    }                                                                          \
  }

#define MFMA_CL                                                                \
  __builtin_amdgcn_s_setprio(1);                                               \
  _Pragma("unroll") for (int mi = 0; mi < 4; ++mi)                             \
  _Pragma("unroll") for (int ni = 0; ni < 4; ++ni)                             \
      acc[mi][ni] = __builtin_amdgcn_mfma_f32_16x16x32_bf16(                   \
          af[mi], bfr[ni], acc[mi][ni], 0, 0, 0);                              \
  __builtin_amdgcn_s_setprio(0);

#define GITER4(T, NV)                                                          \
  {                                                                            \
    if ((T) + 3 < 12) STAGE4(((T) + 3) & 3, ((T) + 3) * 32);                   \
    MFMA_CL;                                                                   \
    asm volatile("s_waitcnt vmcnt(" #NV ")" ::: "memory");                     \
    __builtin_amdgcn_s_barrier();                                              \
    __builtin_amdgcn_sched_barrier(0);                                         \
    FRAGREAD(((T) + 1) & 3);                                                   \
  }

  // prologue: 3 tiles in flight, read tile 0 into regs
  STAGE4(0, 0);
  STAGE4(1, 32);
  STAGE4(2, 64);
  asm volatile("s_waitcnt vmcnt(8)" ::: "memory");
  __builtin_amdgcn_s_barrier();
  __builtin_amdgcn_sched_barrier(0);
  FRAGREAD(0);

  GITER4(0, 8)  GITER4(1, 8)  GITER4(2, 8)  GITER4(3, 8)
  GITER4(4, 8)  GITER4(5, 8)  GITER4(6, 8)  GITER4(7, 8)
  GITER4(8, 8)  GITER4(9, 4)  GITER4(10, 0)
  { MFMA_CL; }   // iter 11: no stage, no read
#undef GITER4
#undef MFMA_CL
#undef FRAGREAD
#undef STAGE4

  // ---- epilogue (bf16 out): acc -> sh (bufs 0-1, disjoint from buf 3) ----
#pragma unroll
  for (int mi = 0; mi < 4; ++mi)
#pragma unroll
    for (int ni = 0; ni < 4; ++ni) {
      int col = wc + ni * 16 + c;
      float bv = bias[n0 + col];
#pragma unroll
      for (int r = 0; r < 4; ++r) {
        int row = wr + mi * 16 + g * 4 + r;
        sh[row * 128 + col] = f2b(acc[mi][ni][r] + bv);
      }
    }
  __syncthreads();
#pragma unroll
  for (int rep = 0; rep < 8; ++rep) {
    int idx = rep * 2048 + tid * 8;      // u16 units; 16 rows per rep
    int row = idx >> 7, col = idx & 127;
    *(u16x8*)(C + (m0 + row) * NCOLS + n0 + col) = *(const u16x8*)&sh[idx];
  }
}

// ------- proj GEMM: round-8 proven 3-buffer counted-vmcnt + T2 swizzle ------
template <int NCOLS, int NTN, int GD8>
__global__ __launch_bounds__(256) void k_gemm(const u16* __restrict__ A,
                                              const u16* __restrict__ B,
                                              const float* __restrict__ bias,
                                              float* __restrict__ C) {
  __shared__ u16 sh[24576];   // 48KB: 3 x (As 8KB + Bs 8KB)
  int bid = blockIdx.x;
  int tile = (bid & 7) * GD8 + (bid >> 3);
  int mt = tile / NTN, nt = tile - mt * NTN;
  long m0 = (long)mt * 128;
  int n0 = nt * 128;
  int tid = threadIdx.x;
  int lane = tid & 63, wid = tid >> 6;
  int wr = (wid >> 1) * 64, wc = (wid & 1) * 64;
  int c = lane & 15, g = lane >> 4;
  int gsw = (g ^ ((c >> 1) & 3)) * 8;

  int srow = wid * 16 + (lane >> 2);
  int scol = ((lane & 3) ^ ((lane >> 3) & 3)) * 8;
  const u16* gA = A + (m0 + srow) * (long)KDIM + scol;
  const u16* gB = B + (long)(n0 + srow) * KDIM + scol;
  int lrow = srow, lseg = (lane & 3) * 8;

  f32x4 acc[4][4] = {};

#define STAGE(BUF, KT)                                                         \
  {                                                                            \
    u16* As_ = sh + (BUF) * 8192;                                              \
    u16* Bs_ = As_ + 4096;                                                     \
    gload_lds16(gA + (KT), &As_[lrow * 32 + lseg]);                            \
    gload_lds16(gA + (KT) + 64L * KDIM, &As_[(lrow + 64) * 32 + lseg]);        \
    gload_lds16(gB + (KT), &Bs_[lrow * 32 + lseg]);                            \
    gload_lds16(gB + (KT) + 64L * KDIM, &Bs_[(lrow + 64) * 32 + lseg]);        \
  }

#define GITER(T, NV)                                                           \
  {                                                                            \
    asm volatile("s_waitcnt vmcnt(" #NV ")" ::: "memory");                     \
    __builtin_amdgcn_s_barrier();                                              \
    const u16* As = sh + ((T) % 3) * 8192;                                     \
    const u16* Bs = As + 4096;                                                 \
    bf16x8 af[4], bfr[4];                                                      \
    _Pragma("unroll") for (int i = 0; i < 4; ++i) {                            \
      af[i]  = ld_bf8(&As[(wr + i * 16 + c) * 32 + gsw]);                      \
      bfr[i] = ld_bf8(&Bs[(wc + i * 16 + c) * 32 + gsw]);                      \
    }                                                                          \
    asm volatile("s_waitcnt lgkmcnt(0)" ::: "memory");                         \
    __builtin_amdgcn_s_barrier();                                              \
    if ((T) + 3 < 12) STAGE((T) % 3, ((T) + 3) * 32);                          \
    __builtin_amdgcn_s_setprio(1);                                             \
    _Pragma("unroll") for (int mi = 0; mi < 4; ++mi)                           \
    _Pragma("unroll") for (int ni = 0; ni < 4; ++ni)                           \
        acc[mi][ni] = __builtin_amdgcn_mfma_f32_16x16x32_bf16(                 \
            af[mi], bfr[ni], acc[mi][ni], 0, 0, 0);                            \
    __builtin_amdgcn_s_setprio(0);                                             \
  }

  STAGE(0, 0);
  STAGE(1, 32);
  STAGE(2, 64);
  GITER(0, 8)  GITER(1, 8)  GITER(2, 8)  GITER(3, 8)
  GITER(4, 8)  GITER(5, 8)  GITER(6, 8)  GITER(7, 8)
  GITER(8, 8)  GITER(9, 8)  GITER(10, 4) GITER(11, 0)
#undef GITER
#undef STAGE

  float* shf = (float*)sh;               // 64 rows x 128 cols f32 = 32KB
#pragma unroll
  for (int chunk = 0; chunk < 2; ++chunk) {
    __syncthreads();
    if ((wr >> 6) == chunk) {
#pragma unroll
      for (int mi = 0; mi < 4; ++mi)
#pragma unroll
        for (int ni = 0; ni < 4; ++ni) {
          int col = wc + ni * 16 + c;
          float bv = bias[n0 + col];
#pragma unroll
          for (int r = 0; r < 4; ++r) {
            int lr = mi * 16 + g * 4 + r;
            shf[lr * 128 + col] = acc[mi][ni][r] + bv;
          }
        }
    }
    __syncthreads();
#pragma unroll
    for (int rep = 0; rep < 8; ++rep) {
      int idx = rep * 1024 + tid * 4;    // f32 units; 8 rows per rep
      int row = idx >> 7, col = idx & 127;
      *(float4*)(C + (m0 + chunk * 64 + row) * NCOLS + n0 + col) =
          *(const float4*)&shf[idx];
    }
  }
}

// ---------------- fused window attention: one wave per (b, h) ----------------
__global__ __launch_bounds__(256) void k_attn(const u16* __restrict__ qkv,
                                              const float* __restrict__ rpbm,
                                              u16* __restrict__ attnout) {
  __shared__ u16 P_lds[4][64 * 64];
  __shared__ u16 vT_lds[4][32 * 64];
  int lane = threadIdx.x & 63, wid = threadIdx.x >> 6;
  int blk = blockIdx.x;                  // 0..6143, w-major for rpbm L2 reuse
  int w = blk / 96;
  int rr = blk - w * 96;
  int j = rr / 3;
  int hb = rr - j * 3;
  int b = j * 64 + w;
  int h = hb * 4 + wid;
  const u16* base = qkv + (size_t)b * (NTOK * 1152);
  int c = lane & 15, g = lane >> 4;

  u16* vt = vT_lds[wid];
  {
    const u16* vbase = base + 2 * DIM + h * HD;
#pragma unroll
    for (int t = 0; t < 4; ++t) {
      int idx = t * 64 + lane;
      int jj = idx >> 2, d0 = (idx & 3) * 8;
      int jr = jj < NTOK ? jj : NTOK - 1;
      u16x8 vv = *(const u16x8*)(vbase + (size_t)jr * 1152 + d0);
#pragma unroll
      for (int dd = 0; dd < 8; ++dd) {
        int d = d0 + dd;
        int byte = (d * 128 + jj * 2) ^ ((d & 7) << 4);
        *(u16*)((char*)vt + byte) = (u16)vv[dd];
      }
    }
  }

  bf16x8 qa[4], kb[4];
#pragma unroll
  for (int mi = 0; mi < 4; ++mi) {
    int row = mi * 16 + c; if (row > NTOK - 1) row = NTOK - 1;
    qa[mi] = ld_bf8(base + (size_t)row * 1152 + h * HD + g * 8);
  }
#pragma unroll
  for (int ni = 0; ni < 4; ++ni) {
    int row = ni * 16 + c; if (row > NTOK - 1) row = NTOK - 1;
    kb[ni] = ld_bf8(base + (size_t)row * 1152 + DIM + h * HD + g * 8);
  }

  f32x4 s[4][4] = {};
#pragma unroll
  for (int mi = 0; mi < 4; ++mi)
#pragma unroll
    for (int ni = 0; ni < 4; ++ni)
      s[mi][ni] = __builtin_amdgcn_mfma_f32_16x16x32_bf16(qa[mi], kb[ni],
                                                          s[mi][ni], 0, 0, 0);

  const float scale = 0.17677669529663687f;   // 32^-0.5
  const f32x4* rp = (const f32x4*)(rpbm + ((size_t)(h * 64 + w)) * 4096);
#pragma unroll
  for (int mi = 0; mi < 4; ++mi)
#pragma unroll
    for (int ni = 0; ni < 4; ++ni) {
      f32x4 rv = rp[(mi * 4 + ni) * 64 + lane];
#pragma unroll
      for (int r = 0; r < 4; ++r)
        s[mi][ni][r] = s[mi][ni][r] * scale + rv[r];
    }

#pragma unroll
  for (int mi = 0; mi < 4; ++mi)
#pragma unroll
    for (int r = 0; r < 4; ++r) {
      float mx = fmaxf(fmaxf(s[mi][0][r], s[mi][1][r]),
                       fmaxf(s[mi][2][r], s[mi][3][r]));
      mx = fmaxf(mx, __shfl_xor(mx, 1));
      mx = fmaxf(mx, __shfl_xor(mx, 2));
      mx = fmaxf(mx, __shfl_xor(mx, 4));
      mx = fmaxf(mx, __shfl_xor(mx, 8));
      float sum = 0.f;
#pragma unroll
      for (int ni = 0; ni < 4; ++ni) {
        float p = __expf(s[mi][ni][r] - mx);
        s[mi][ni][r] = p;
        sum += p;
      }
      sum += __shfl_xor(sum, 1);
      sum += __shfl_xor(sum, 2);
      sum += __shfl_xor(sum, 4);
      sum += __shfl_xor(sum, 8);
      float inv = __builtin_amdgcn_rcpf(sum);
#pragma unroll
      for (int ni = 0; ni < 4; ++ni) s[mi][ni][r] *= inv;
    }

  u16* pl = P_lds[wid];
#pragma unroll
  for (int mi = 0; mi < 4; ++mi)
#pragma unroll
    for (int ni = 0; ni < 4; ++ni) {
      int col = ni * 16 + c;
#pragma unroll
      for (int r = 0; r < 4; ++r) {
        int row = mi * 16 + g * 4 + r;
        int byte = (row * 128 + col * 2) ^ ((row & 7) << 4);
        *(u16*)((char*)pl + byte) = f2b(s[mi][ni][r]);
      }
    }
  asm volatile("s_waitcnt lgkmcnt(0)" ::: "memory");

  f32x4 o[4][2] = {};
#pragma unroll
  for (int ks = 0; ks < 2; ++ks) {
    bf16x8 vb[2];
#pragma unroll
    for (int n2 = 0; n2 < 2; ++n2) {
      int d = n2 * 16 + c;
      int byte = (d * 128 + ks * 64 + g * 16) ^ ((d & 7) << 4);
      vb[n2] = __builtin_bit_cast(bf16x8, *(const u16x8*)((const char*)vt + byte));
    }
#pragma unroll
    for (int mi = 0; mi < 4; ++mi) {
      int row = mi * 16 + c;
      int byte = (row * 128 + ks * 64 + g * 16) ^ ((row & 7) << 4);
      bf16x8 pa = __builtin_bit_cast(bf16x8, *(const u16x8*)((const char*)pl + byte));
#pragma unroll
      for (int n2 = 0; n2 < 2; ++n2)
        o[mi][n2] = __builtin_amdgcn_mfma_f32_16x16x32_bf16(pa, vb[n2],
                                                            o[mi][n2], 0, 0, 0);
    }
  }

  u16* obase = attnout + (size_t)b * (NTOK * DIM) + h * HD;
#pragma unroll
  for (int mi = 0; mi < 4; ++mi)
#pragma unroll
    for (int r = 0; r < 4; ++r) {
      int row = mi * 16 + g * 4 + r;
      if (row < NTOK) {
#pragma unroll
        for (int n2 = 0; n2 < 2; ++n2)
          obase[(size_t)row * DIM + n2 * 16 + c] = f2b(o[mi][n2][r]);
      }
    }
}

// ---------------------------------------------------------------------------
extern "C" void kernel_launch(void* const* d_in, const int* in_sizes, int n_in,
                              void* d_out, int out_size, void* d_ws, size_t ws_size,
                              hipStream_t stream) {
  const float* x       = (const float*)d_in[0];
  const float* qkv_w   = (const float*)d_in[1];
  const float* qkv_b   = (const float*)d_in[2];
  const float* proj_w  = (const float*)d_in[3];
  const float* proj_b  = (const float*)d_in[4];
  const float* bias_tb = (const float*)d_in[5];
  const float* mask    = (const float*)d_in[6];
  const int*   rel_idx = (const int*)d_in[7];
  float* out = (float*)d_out;

  char* ws = (char*)d_ws;
  u16*   xb      = (u16*)(ws + 0);                  //  77,070,336  x bf16
  u16*   wqkvb   = (u16*)(ws + 77070336);           //     884,736  qkv_w bf16
  u16*   wprojb  = (u16*)(ws + 77955072);           //     294,912  proj_w bf16
  float* rpbm    = (float*)(ws + 78249984);         //  12,582,912  bias+mask
  u16*   qkv     = (u16*)(ws + 90832896);           // 231,211,008  qkv bf16
  u16*   attnout = (u16*)(ws + 322043904);          //  77,070,336  attn out bf16

  // 1) prep: all casts + fused bias+mask table
  k_prep<<<50496, 256, 0, stream>>>(x, xb, qkv_w, wqkvb, proj_w, wprojb,
                                    bias_tb, mask, rel_idx, rpbm);

  // 2) QKV GEMM (4-buffer one-barrier): [100352,384] x [1152,384]^T -> bf16
  k_gemm4<1152, 9, 882><<<7056, 256, 0, stream>>>(xb, wqkvb, qkv_b, qkv);

  // 3) window attention -> bf16 [100352,384]
  k_attn<<<6144, 256, 0, stream>>>(qkv, rpbm, attnout);

  // 4) proj GEMM (round-8 structure): [100352,384] x [384,384]^T -> f32 d_out
  k_gemm<384, 3, 294><<<2352, 256, 0, stream>>>(attnout, wprojb, proj_b, out);

  (void)in_sizes; (void)n_in; (void)out_size; (void)ws_size;
}

// Round 10
// 348.000 us; speedup vs baseline: 1.0643x; 1.0643x over previous
//
#include <hip/hip_runtime.h>
#include <hip/hip_bf16.h>
#include <cstdint>
#include <cstddef>

// Problem constants
#define NTOK 49
#define DIM 384
#define KDIM 384
#define HEADS 12
#define HD 32
#define BATCH 2048
#define MROWS (BATCH * NTOK)   // 100352 = 784 * 128

typedef unsigned short u16;
typedef __bf16 bf16x8 __attribute__((ext_vector_type(8)));
typedef unsigned short u16x8 __attribute__((ext_vector_type(8)));
typedef float f32x4 __attribute__((ext_vector_type(4)));

__device__ __forceinline__ u16 f2b(float f) {
  union { float f; unsigned u; } v; v.f = f;
  unsigned r = v.u + 0x7fffu + ((v.u >> 16) & 1u);   // RNE bf16
  return (u16)(r >> 16);
}

__device__ __forceinline__ bf16x8 ld_bf8(const u16* p) {
  u16x8 u = *(const u16x8*)p;
  return __builtin_bit_cast(bf16x8, u);
}

__device__ __forceinline__ void gload_lds16(const void* g, void* l) {
  __builtin_amdgcn_global_load_lds(
      (const __attribute__((address_space(1))) unsigned*)g,
      (__attribute__((address_space(3))) unsigned*)l, 16, 0, 0);
}

// ---------------- prep: x/w casts + fused bias+mask table, one launch -------
__global__ __launch_bounds__(256) void k_prep(const float* __restrict__ x,
                                              u16* __restrict__ xb,
                                              const float* __restrict__ qkv_w,
                                              u16* __restrict__ wqkvb,
                                              const float* __restrict__ proj_w,
                                              u16* __restrict__ wprojb,
                                              const float* __restrict__ bias_table,
                                              const float* __restrict__ mask,
                                              const int* __restrict__ rel_idx,
                                              float* __restrict__ rpbm) {
  int blk = blockIdx.x;
  if (blk < 38208) {
    const float* in;
    u16* out;
    int i;
    if (blk < 37632) {
      in = x; out = xb; i = blk * 256 + threadIdx.x;
    } else if (blk < 38064) {
      in = qkv_w; out = wqkvb; i = (blk - 37632) * 256 + threadIdx.x;
    } else {
      in = proj_w; out = wprojb; i = (blk - 38064) * 256 + threadIdx.x;
    }
    float4 v = ((const float4*)in)[i];
    ushort4 o;
    o.x = f2b(v.x); o.y = f2b(v.y); o.z = f2b(v.z); o.w = f2b(v.w);
    ((ushort4*)out)[i] = o;
  } else {
    int idx = (blk - 38208) * 256 + threadIdx.x;   // 12*64*4096 entries
    int r  = idx & 3;
    int l  = (idx >> 2) & 63;
    int ni = (idx >> 8) & 3;
    int mi = (idx >> 10) & 3;
    int w  = (idx >> 12) & 63;
    int h  = idx >> 18;
    int row = mi * 16 + (l >> 4) * 4 + r;
    int col = ni * 16 + (l & 15);
    float v = -1e30f;
    if (row < NTOK && col < NTOK)
      v = bias_table[rel_idx[row * NTOK + col] * HEADS + h] +
          mask[(w * NTOK + row) * NTOK + col];
    rpbm[idx] = v;
  }
}

// ------- QKV GEMM: 3-buffer, ONE barrier per K-step, reg-prefetched frags ---
// Iter t: MFMA(regs tile t) ; vmcnt(N) ; s_barrier ; STAGE(t+3 -> buf t%3) ;
//         FRAGREAD(t+1 -> regs).
// WAR: all waves' ds_reads of buf t%3 (tile t) complete before MFMA(t), hence
// before barrier(t); the stage into buf t%3 issues AFTER barrier(t). Safe with
// one barrier. vmcnt: at iter t outstanding = stage(t-1) [4 loads]; need tile
// t+1 (staged at t-2) -> vmcnt(4); tail: vmcnt(0) at iter 10.
// T2 swizzle: linear LDS dest, pre-swizzled global source seg, swizzled read.
template <int NCOLS, int NTN, int GD8>
__global__ __launch_bounds__(256) void k_gemm3p(const u16* __restrict__ A,
                                                const u16* __restrict__ B,
                                                const float* __restrict__ bias,
                                                u16* __restrict__ C) {
  __shared__ u16 sh[24576];   // 48KB: 3 x (As 8KB + Bs 8KB); epilogue reuses 32KB
  int bid = blockIdx.x;
  int tile = (bid & 7) * GD8 + (bid >> 3);   // XCD-contiguous (grid % 8 == 0)
  int mt = tile / NTN, nt = tile - mt * NTN;
  long m0 = (long)mt * 128;
  int n0 = nt * 128;
  int tid = threadIdx.x;
  int lane = tid & 63, wid = tid >> 6;
  int wr = (wid >> 1) * 64, wc = (wid & 1) * 64;
  int c = lane & 15, g = lane >> 4;
  int gsw = (g ^ ((c >> 1) & 3)) * 8;        // swizzled read segment (u16 units)

  int srow = wid * 16 + (lane >> 2);
  int scol = ((lane & 3) ^ ((lane >> 3) & 3)) * 8;   // pre-swizzled global seg
  const u16* gA = A + (m0 + srow) * (long)KDIM + scol;
  const u16* gB = B + (long)(n0 + srow) * KDIM + scol;
  int lrow = srow, lseg = (lane & 3) * 8;            // linear LDS dest

  f32x4 acc[4][4] = {};
  bf16x8 af[4], bfr[4];

#define STAGE3(BUF, KT)                                                        \
  {                                                                            \
    u16* As_ = sh + (BUF) * 8192;                                              \
    u16* Bs_ = As_ + 4096;                                                     \
    gload_lds16(gA + (KT), &As_[lrow * 32 + lseg]);                            \
    gload_lds16(gA + (KT) + 64L * KDIM, &As_[(lrow + 64) * 32 + lseg]);        \
    gload_lds16(gB + (KT), &Bs_[lrow * 32 + lseg]);                            \
    gload_lds16(gB + (KT) + 64L * KDIM, &Bs_[(lrow + 64) * 32 + lseg]);        \
  }

#define FRAGREAD(BUF)                                                          \
  {                                                                            \
    const u16* As = sh + (BUF) * 8192;                                         \
    const u16* Bs = As + 4096;                                                 \
    _Pragma("unroll") for (int i = 0; i < 4; ++i) {                            \
      af[i]  = ld_bf8(&As[(wr + i * 16 + c) * 32 + gsw]);                      \
      bfr[i] = ld_bf8(&Bs[(wc + i * 16 + c) * 32 + gsw]);                      \
    }                                                                          \
  }

#define MFMA_CL                                                                \
  __builtin_amdgcn_s_setprio(1);                                               \
  _Pragma("unroll") for (int mi = 0; mi < 4; ++mi)                             \
  _Pragma("unroll") for (int ni = 0; ni < 4; ++ni)                             \
      acc[mi][ni] = __builtin_amdgcn_mfma_f32_16x16x32_bf16(                   \
          af[mi], bfr[ni], acc[mi][ni], 0, 0, 0);                              \
  __builtin_amdgcn_s_setprio(0);

#define GITER3(T, NV)                                                          \
  {                                                                            \
    MFMA_CL;                                                                   \
    asm volatile("s_waitcnt vmcnt(" #NV ")" ::: "memory");                     \
    __builtin_amdgcn_s_barrier();                                              \
    __builtin_amdgcn_sched_barrier(0);                                         \
    if ((T) + 3 < 12) STAGE3((T) % 3, ((T) + 3) * 32);                         \
    FRAGREAD(((T) + 1) % 3);                                                   \
  }

  // prologue: 3 tiles staged, tile 0 into regs
  STAGE3(0, 0);
  STAGE3(1, 32);
  STAGE3(2, 64);
  asm volatile("s_waitcnt vmcnt(8)" ::: "memory");
  __builtin_amdgcn_s_barrier();
  __builtin_amdgcn_sched_barrier(0);
  FRAGREAD(0);

  GITER3(0, 4)  GITER3(1, 4)  GITER3(2, 4)  GITER3(3, 4)
  GITER3(4, 4)  GITER3(5, 4)  GITER3(6, 4)  GITER3(7, 4)
  GITER3(8, 4)  GITER3(9, 4)  GITER3(10, 0)
  { MFMA_CL; }   // iter 11: pure MFMA, no stage/read
#undef GITER3
#undef MFMA_CL
#undef FRAGREAD
#undef STAGE3

  // ---- epilogue (bf16 out): writes bufs 0-1 (disjoint from buf 2, which
  // other waves may still be FRAGREAD(11)-ing) ----
#pragma unroll
  for (int mi = 0; mi < 4; ++mi)
#pragma unroll
    for (int ni = 0; ni < 4; ++ni) {
      int col = wc + ni * 16 + c;
      float bv = bias[n0 + col];
#pragma unroll
      for (int r = 0; r < 4; ++r) {
        int row = wr + mi * 16 + g * 4 + r;
        sh[row * 128 + col] = f2b(acc[mi][ni][r] + bv);
      }
    }
  __syncthreads();
#pragma unroll
  for (int rep = 0; rep < 8; ++rep) {
    int idx = rep * 2048 + tid * 8;      // u16 units; 16 rows per rep
    int row = idx >> 7, col = idx & 127;
    *(u16x8*)(C + (m0 + row) * NCOLS + n0 + col) = *(const u16x8*)&sh[idx];
  }
}

// ------- proj GEMM: round-8 proven 3-buffer counted-vmcnt + T2 swizzle ------
template <int NCOLS, int NTN, int GD8>
__global__ __launch_bounds__(256) void k_gemm(const u16* __restrict__ A,
                                              const u16* __restrict__ B,
                                              const float* __restrict__ bias,
                                              float* __restrict__ C) {
  __shared__ u16 sh[24576];   // 48KB: 3 x (As 8KB + Bs 8KB)
  int bid = blockIdx.x;
  int tile = (bid & 7) * GD8 + (bid >> 3);
  int mt = tile / NTN, nt = tile - mt * NTN;
  long m0 = (long)mt * 128;
  int n0 = nt * 128;
  int tid = threadIdx.x;
  int lane = tid & 63, wid = tid >> 6;
  int wr = (wid >> 1) * 64, wc = (wid & 1) * 64;
  int c = lane & 15, g = lane >> 4;
  int gsw = (g ^ ((c >> 1) & 3)) * 8;

  int srow = wid * 16 + (lane >> 2);
  int scol = ((lane & 3) ^ ((lane >> 3) & 3)) * 8;
  const u16* gA = A + (m0 + srow) * (long)KDIM + scol;
  const u16* gB = B + (long)(n0 + srow) * KDIM + scol;
  int lrow = srow, lseg = (lane & 3) * 8;

  f32x4 acc[4][4] = {};

#define STAGE(BUF, KT)                                                         \
  {                                                                            \
    u16* As_ = sh + (BUF) * 8192;                                              \
    u16* Bs_ = As_ + 4096;                                                     \
    gload_lds16(gA + (KT), &As_[lrow * 32 + lseg]);                            \
    gload_lds16(gA + (KT) + 64L * KDIM, &As_[(lrow + 64) * 32 + lseg]);        \
    gload_lds16(gB + (KT), &Bs_[lrow * 32 + lseg]);                            \
    gload_lds16(gB + (KT) + 64L * KDIM, &Bs_[(lrow + 64) * 32 + lseg]);        \
  }

#define GITER(T, NV)                                                           \
  {                                                                            \
    asm volatile("s_waitcnt vmcnt(" #NV ")" ::: "memory");                     \
    __builtin_amdgcn_s_barrier();                                              \
    const u16* As = sh + ((T) % 3) * 8192;                                     \
    const u16* Bs = As + 4096;                                                 \
    bf16x8 af[4], bfr[4];                                                      \
    _Pragma("unroll") for (int i = 0; i < 4; ++i) {                            \
      af[i]  = ld_bf8(&As[(wr + i * 16 + c) * 32 + gsw]);                      \
      bfr[i] = ld_bf8(&Bs[(wc + i * 16 + c) * 32 + gsw]);                      \
    }                                                                          \
    asm volatile("s_waitcnt lgkmcnt(0)" ::: "memory");                         \
    __builtin_amdgcn_s_barrier();                                              \
    if ((T) + 3 < 12) STAGE((T) % 3, ((T) + 3) * 32);                          \
    __builtin_amdgcn_s_setprio(1);                                             \
    _Pragma("unroll") for (int mi = 0; mi < 4; ++mi)                           \
    _Pragma("unroll") for (int ni = 0; ni < 4; ++ni)                           \
        acc[mi][ni] = __builtin_amdgcn_mfma_f32_16x16x32_bf16(                 \
            af[mi], bfr[ni], acc[mi][ni], 0, 0, 0);                            \
    __builtin_amdgcn_s_setprio(0);                                             \
  }

  STAGE(0, 0);
  STAGE(1, 32);
  STAGE(2, 64);
  GITER(0, 8)  GITER(1, 8)  GITER(2, 8)  GITER(3, 8)
  GITER(4, 8)  GITER(5, 8)  GITER(6, 8)  GITER(7, 8)
  GITER(8, 8)  GITER(9, 8)  GITER(10, 4) GITER(11, 0)
#undef GITER
#undef STAGE

  float* shf = (float*)sh;               // 64 rows x 128 cols f32 = 32KB
#pragma unroll
  for (int chunk = 0; chunk < 2; ++chunk) {
    __syncthreads();
    if ((wr >> 6) == chunk) {
#pragma unroll
      for (int mi = 0; mi < 4; ++mi)
#pragma unroll
        for (int ni = 0; ni < 4; ++ni) {
          int col = wc + ni * 16 + c;
          float bv = bias[n0 + col];
#pragma unroll
          for (int r = 0; r < 4; ++r) {
            int lr = mi * 16 + g * 4 + r;
            shf[lr * 128 + col] = acc[mi][ni][r] + bv;
          }
        }
    }
    __syncthreads();
#pragma unroll
    for (int rep = 0; rep < 8; ++rep) {
      int idx = rep * 1024 + tid * 4;    // f32 units; 8 rows per rep
      int row = idx >> 7, col = idx & 127;
      *(float4*)(C + (m0 + chunk * 64 + row) * NCOLS + n0 + col) =
          *(const float4*)&shf[idx];
    }
  }
}

// ---------------- fused window attention: one wave per (b, h) ----------------
__global__ __launch_bounds__(256) void k_attn(const u16* __restrict__ qkv,
                                              const float* __restrict__ rpbm,
                                              u16* __restrict__ attnout) {
  __shared__ u16 P_lds[4][64 * 64];
  __shared__ u16 vT_lds[4][32 * 64];
  int lane = threadIdx.x & 63, wid = threadIdx.x >> 6;
  int blk = blockIdx.x;                  // 0..6143, w-major for rpbm L2 reuse
  int w = blk / 96;
  int rr = blk - w * 96;
  int j = rr / 3;
  int hb = rr - j * 3;
  int b = j * 64 + w;
  int h = hb * 4 + wid;
  const u16* base = qkv + (size_t)b * (NTOK * 1152);
  int c = lane & 15, g = lane >> 4;

  u16* vt = vT_lds[wid];
  {
    const u16* vbase = base + 2 * DIM + h * HD;
#pragma unroll
    for (int t = 0; t < 4; ++t) {
      int idx = t * 64 + lane;
      int jj = idx >> 2, d0 = (idx & 3) * 8;
      int jr = jj < NTOK ? jj : NTOK - 1;
      u16x8 vv = *(const u16x8*)(vbase + (size_t)jr * 1152 + d0);
#pragma unroll
      for (int dd = 0; dd < 8; ++dd) {
        int d = d0 + dd;
        int byte = (d * 128 + jj * 2) ^ ((d & 7) << 4);
        *(u16*)((char*)vt + byte) = (u16)vv[dd];
      }
    }
  }

  bf16x8 qa[4], kb[4];
#pragma unroll
  for (int mi = 0; mi < 4; ++mi) {
    int row = mi * 16 + c; if (row > NTOK - 1) row = NTOK - 1;
    qa[mi] = ld_bf8(base + (size_t)row * 1152 + h * HD + g * 8);
  }
#pragma unroll
  for (int ni = 0; ni < 4; ++ni) {
    int row = ni * 16 + c; if (row > NTOK - 1) row = NTOK - 1;
    kb[ni] = ld_bf8(base + (size_t)row * 1152 + DIM + h * HD + g * 8);
  }

  f32x4 s[4][4] = {};
#pragma unroll
  for (int mi = 0; mi < 4; ++mi)
#pragma unroll
    for (int ni = 0; ni < 4; ++ni)
      s[mi][ni] = __builtin_amdgcn_mfma_f32_16x16x32_bf16(qa[mi], kb[ni],
                                                          s[mi][ni], 0, 0, 0);

  const float scale = 0.17677669529663687f;   // 32^-0.5
  const f32x4* rp = (const f32x4*)(rpbm + ((size_t)(h * 64 + w)) * 4096);
#pragma unroll
  for (int mi = 0; mi < 4; ++mi)
#pragma unroll
    for (int ni = 0; ni < 4; ++ni) {
      f32x4 rv = rp[(mi * 4 + ni) * 64 + lane];
#pragma unroll
      for (int r = 0; r < 4; ++r)
        s[mi][ni][r] = s[mi][ni][r] * scale + rv[r];
    }

#pragma unroll
  for (int mi = 0; mi < 4; ++mi)
#pragma unroll
    for (int r = 0; r < 4; ++r) {
      float mx = fmaxf(fmaxf(s[mi][0][r], s[mi][1][r]),
                       fmaxf(s[mi][2][r], s[mi][3][r]));
      mx = fmaxf(mx, __shfl_xor(mx, 1));
      mx = fmaxf(mx, __shfl_xor(mx, 2));
      mx = fmaxf(mx, __shfl_xor(mx, 4));
      mx = fmaxf(mx, __shfl_xor(mx, 8));
      float sum = 0.f;
#pragma unroll
      for (int ni = 0; ni < 4; ++ni) {
        float p = __expf(s[mi][ni][r] - mx);
        s[mi][ni][r] = p;
        sum += p;
      }
      sum += __shfl_xor(sum, 1);
      sum += __shfl_xor(sum, 2);
      sum += __shfl_xor(sum, 4);
      sum += __shfl_xor(sum, 8);
      float inv = __builtin_amdgcn_rcpf(sum);
#pragma unroll
      for (int ni = 0; ni < 4; ++ni) s[mi][ni][r] *= inv;
    }

  u16* pl = P_lds[wid];
#pragma unroll
  for (int mi = 0; mi < 4; ++mi)
#pragma unroll
    for (int ni = 0; ni < 4; ++ni) {
      int col = ni * 16 + c;
#pragma unroll
      for (int r = 0; r < 4; ++r) {
        int row = mi * 16 + g * 4 + r;
        int byte = (row * 128 + col * 2) ^ ((row & 7) << 4);
        *(u16*)((char*)pl + byte) = f2b(s[mi][ni][r]);
      }
    }
  asm volatile("s_waitcnt lgkmcnt(0)" ::: "memory");

  f32x4 o[4][2] = {};
#pragma unroll
  for (int ks = 0; ks < 2; ++ks) {
    bf16x8 vb[2];
#pragma unroll
    for (int n2 = 0; n2 < 2; ++n2) {
      int d = n2 * 16 + c;
      int byte = (d * 128 + ks * 64 + g * 16) ^ ((d & 7) << 4);
      vb[n2] = __builtin_bit_cast(bf16x8, *(const u16x8*)((const char*)vt + byte));
    }
#pragma unroll
    for (int mi = 0; mi < 4; ++mi) {
      int row = mi * 16 + c;
      int byte = (row * 128 + ks * 64 + g * 16) ^ ((row & 7) << 4);
      bf16x8 pa = __builtin_bit_cast(bf16x8, *(const u16x8*)((const char*)pl + byte));
#pragma unroll
      for (int n2 = 0; n2 < 2; ++n2)
        o[mi][n2] = __builtin_amdgcn_mfma_f32_16x16x32_bf16(pa, vb[n2],
                                                            o[mi][n2], 0, 0, 0);
    }
  }

  u16* obase = attnout + (size_t)b * (NTOK * DIM) + h * HD;
#pragma unroll
  for (int mi = 0; mi < 4; ++mi)
#pragma unroll
    for (int r = 0; r < 4; ++r) {
      int row = mi * 16 + g * 4 + r;
      if (row < NTOK) {
#pragma unroll
        for (int n2 = 0; n2 < 2; ++n2)
          obase[(size_t)row * DIM + n2 * 16 + c] = f2b(o[mi][n2][r]);
      }
    }
}

// ---------------------------------------------------------------------------
extern "C" void kernel_launch(void* const* d_in, const int* in_sizes, int n_in,
                              void* d_out, int out_size, void* d_ws, size_t ws_size,
                              hipStream_t stream) {
  const float* x       = (const float*)d_in[0];
  const float* qkv_w   = (const float*)d_in[1];
  const float* qkv_b   = (const float*)d_in[2];
  const float* proj_w  = (const float*)d_in[3];
  const float* proj_b  = (const float*)d_in[4];
  const float* bias_tb = (const float*)d_in[5];
  const float* mask    = (const float*)d_in[6];
  const int*   rel_idx = (const int*)d_in[7];
  float* out = (float*)d_out;

  char* ws = (char*)d_ws;
  u16*   xb      = (u16*)(ws + 0);                  //  77,070,336  x bf16
  u16*   wqkvb   = (u16*)(ws + 77070336);           //     884,736  qkv_w bf16
  u16*   wprojb  = (u16*)(ws + 77955072);           //     294,912  proj_w bf16
  float* rpbm    = (float*)(ws + 78249984);         //  12,582,912  bias+mask
  u16*   qkv     = (u16*)(ws + 90832896);           // 231,211,008  qkv bf16
  u16*   attnout = (u16*)(ws + 322043904);          //  77,070,336  attn out bf16

  // 1) prep: all casts + fused bias+mask table
  k_prep<<<50496, 256, 0, stream>>>(x, xb, qkv_w, wqkvb, proj_w, wprojb,
                                    bias_tb, mask, rel_idx, rpbm);

  // 2) QKV GEMM (3-buffer, one-barrier, reg-prefetch): -> bf16 [100352,1152]
  k_gemm3p<1152, 9, 882><<<7056, 256, 0, stream>>>(xb, wqkvb, qkv_b, qkv);

  // 3) window attention -> bf16 [100352,384]
  k_attn<<<6144, 256, 0, stream>>>(qkv, rpbm, attnout);

  // 4) proj GEMM (round-8 structure): [100352,384] x [384,384]^T -> f32 d_out
  k_gemm<384, 3, 294><<<2352, 256, 0, stream>>>(attnout, wprojb, proj_b, out);

  (void)in_sizes; (void)n_in; (void)out_size; (void)ws_size;
}

// Round 11
// 342.282 us; speedup vs baseline: 1.0820x; 1.0167x over previous
//
#include <hip/hip_runtime.h>
#include <hip/hip_bf16.h>
#include <cstdint>
#include <cstddef>

// Problem constants
#define NTOK 49
#define DIM 384
#define KDIM 384
#define HEADS 12
#define HD 32
#define BATCH 2048
#define MROWS (BATCH * NTOK)   // 100352 = 392 * 256

typedef unsigned short u16;
typedef __bf16 bf16x8 __attribute__((ext_vector_type(8)));
typedef unsigned short u16x8 __attribute__((ext_vector_type(8)));
typedef float f32x4 __attribute__((ext_vector_type(4)));

__device__ __forceinline__ u16 f2b(float f) {
  union { float f; unsigned u; } v; v.f = f;
  unsigned r = v.u + 0x7fffu + ((v.u >> 16) & 1u);   // RNE bf16
  return (u16)(r >> 16);
}

__device__ __forceinline__ bf16x8 ld_bf8(const u16* p) {
  u16x8 u = *(const u16x8*)p;
  return __builtin_bit_cast(bf16x8, u);
}

__device__ __forceinline__ void gload_lds16(const void* g, void* l) {
  __builtin_amdgcn_global_load_lds(
      (const __attribute__((address_space(1))) unsigned*)g,
      (__attribute__((address_space(3))) unsigned*)l, 16, 0, 0);
}

// ---------------- prep: x/w casts + fused bias+mask table, one launch -------
__global__ __launch_bounds__(256) void k_prep(const float* __restrict__ x,
                                              u16* __restrict__ xb,
                                              const float* __restrict__ qkv_w,
                                              u16* __restrict__ wqkvb,
                                              const float* __restrict__ proj_w,
                                              u16* __restrict__ wprojb,
                                              const float* __restrict__ bias_table,
                                              const float* __restrict__ mask,
                                              const int* __restrict__ rel_idx,
                                              float* __restrict__ rpbm) {
  int blk = blockIdx.x;
  if (blk < 38208) {
    const float* in;
    u16* out;
    int i;
    if (blk < 37632) {
      in = x; out = xb; i = blk * 256 + threadIdx.x;
    } else if (blk < 38064) {
      in = qkv_w; out = wqkvb; i = (blk - 37632) * 256 + threadIdx.x;
    } else {
      in = proj_w; out = wprojb; i = (blk - 38064) * 256 + threadIdx.x;
    }
    float4 v = ((const float4*)in)[i];
    ushort4 o;
    o.x = f2b(v.x); o.y = f2b(v.y); o.z = f2b(v.z); o.w = f2b(v.w);
    ((ushort4*)out)[i] = o;
  } else {
    int idx = (blk - 38208) * 256 + threadIdx.x;   // 12*64*4096 entries
    int r  = idx & 3;
    int l  = (idx >> 2) & 63;
    int ni = (idx >> 8) & 3;
    int mi = (idx >> 10) & 3;
    int w  = (idx >> 12) & 63;
    int h  = idx >> 18;
    int row = mi * 16 + (l >> 4) * 4 + r;
    int col = ni * 16 + (l & 15);
    float v = -1e30f;
    if (row < NTOK && col < NTOK)
      v = bias_table[rel_idx[row * NTOK + col] * HEADS + h] +
          mask[(w * NTOK + row) * NTOK + col];
    rpbm[idx] = v;
  }
}

// ------- NT GEMM: 256x128 tile, 512 thr / 8 waves, 3-buf counted vmcnt ------
// One barrier per K-step, reg-prefetched fragments, T2 swizzle.
// Iter t: MFMA(regs tile t) ; vmcnt(N) ; s_barrier ; STAGE(t+3 -> buf t%3) ;
//         FRAGREAD(t+1 -> regs).
// Buffers (u16 units): buf k at sh + k*12288 (As 8192 = 256x32, Bs 4096 = 128x32).
// Staging: 3 gload_lds16/thread (A rows 0-127, A rows 128-255, B rows 0-127);
// vmcnt(3) steady (stage(t+2)'s 3 loads in flight), vmcnt(0) at t=10.
// WAR: one barrier suffices (reads of buf t%3 retire before MFMA(t) -> before
// barrier(t); restage of that buf issues after barrier(t)). Epilogue overlaps
// buf2 -> explicit barrier after final MFMA.
template <int OUT_BF16, int NCOLS, int NTN, int GD8>
__global__ __launch_bounds__(512, 4) void k_gemm256(const u16* __restrict__ A,
                                                    const u16* __restrict__ B,
                                                    const float* __restrict__ bias,
                                                    void* __restrict__ Cv) {
  __shared__ u16 sh[36864];   // 72 KB: 3 x 24 KB; epilogue reuses 64 KB
  int bid = blockIdx.x;
  int tile = (bid & 7) * GD8 + (bid >> 3);   // XCD-contiguous (grid % 8 == 0)
  int mt = tile / NTN, nt = tile - mt * NTN;
  long m0 = (long)mt * 256;
  int n0 = nt * 128;
  int tid = threadIdx.x;
  int lane = tid & 63, wid = tid >> 6;           // 8 waves
  int wr = (wid >> 1) * 64, wc = (wid & 1) * 64; // 4M x 2N wave grid
  int c = lane & 15, g = lane >> 4;
  int gsw = (g ^ ((c >> 1) & 3)) * 8;            // swizzled read segment

  // staging: per wave 16 rows (srow), LDS byte = base + wid*1024 + lane*16
  int srow = wid * 16 + (lane >> 2);             // 0..127
  int scol = ((lane & 3) ^ ((lane >> 3) & 3)) * 8;  // pre-swizzled global seg
  const u16* gA = A + (m0 + srow) * (long)KDIM + scol;
  const u16* gB = B + (long)(n0 + srow) * KDIM + scol;
  int lrow = srow, lseg = (lane & 3) * 8;        // linear LDS dest

  f32x4 acc[4][4] = {};
  bf16x8 af[4], bfr[4];

#define STAGE256(BUF, KT)                                                      \
  {                                                                            \
    u16* As_ = sh + (BUF) * 12288;                                             \
    u16* Bs_ = As_ + 8192;                                                     \
    gload_lds16(gA + (KT), &As_[lrow * 32 + lseg]);                            \
    gload_lds16(gA + (KT) + 128L * KDIM, &As_[(lrow + 128) * 32 + lseg]);      \
    gload_lds16(gB + (KT), &Bs_[lrow * 32 + lseg]);                            \
  }

#define FRAGREAD(BUF)                                                          \
  {                                                                            \
    const u16* As = sh + (BUF) * 12288;                                        \
    const u16* Bs = As + 8192;                                                 \
    _Pragma("unroll") for (int i = 0; i < 4; ++i) {                            \
      af[i]  = ld_bf8(&As[(wr + i * 16 + c) * 32 + gsw]);                      \
      bfr[i] = ld_bf8(&Bs[(wc + i * 16 + c) * 32 + gsw]);                      \
    }                                                                          \
  }

#define MFMA_CL                                                                \
  __builtin_amdgcn_s_setprio(1);                                               \
  _Pragma("unroll") for (int mi = 0; mi < 4; ++mi)                             \
  _Pragma("unroll") for (int ni = 0; ni < 4; ++ni)                             \
      acc[mi][ni] = __builtin_amdgcn_mfma_f32_16x16x32_bf16(                   \
          af[mi], bfr[ni], acc[mi][ni], 0, 0, 0);                              \
  __builtin_amdgcn_s_setprio(0);

#define GITER(T, NV)                                                           \
  {                                                                            \
    MFMA_CL;                                                                   \
    asm volatile("s_waitcnt vmcnt(" #NV ")" ::: "memory");                     \
    __builtin_amdgcn_s_barrier();                                              \
    __builtin_amdgcn_sched_barrier(0);                                         \
    if ((T) + 3 < 12) STAGE256((T) % 3, ((T) + 3) * 32);                       \
    FRAGREAD(((T) + 1) % 3);                                                   \
  }

  // prologue: stage 3 tiles (9 loads), read tile 0 into regs
  STAGE256(0, 0);
  STAGE256(1, 32);
  STAGE256(2, 64);
  asm volatile("s_waitcnt vmcnt(6)" ::: "memory");
  __builtin_amdgcn_s_barrier();
  __builtin_amdgcn_sched_barrier(0);
  FRAGREAD(0);

  GITER(0, 3)  GITER(1, 3)  GITER(2, 3)  GITER(3, 3)
  GITER(4, 3)  GITER(5, 3)  GITER(6, 3)  GITER(7, 3)
  GITER(8, 3)  GITER(9, 3)  GITER(10, 0)
  { MFMA_CL; }   // iter 11: pure MFMA
  __builtin_amdgcn_s_barrier();   // all waves' tile-11 reads retired before
                                  // epilogue overwrites buffer space
#undef GITER
#undef MFMA_CL
#undef FRAGREAD
#undef STAGE256

  if (OUT_BF16) {
    u16* C = (u16*)Cv;
#pragma unroll
    for (int mi = 0; mi < 4; ++mi)
#pragma unroll
      for (int ni = 0; ni < 4; ++ni) {
        int col = wc + ni * 16 + c;
        float bv = bias[n0 + col];
#pragma unroll
        for (int r = 0; r < 4; ++r) {
          int row = wr + mi * 16 + g * 4 + r;       // 0..255
          sh[row * 128 + col] = f2b(acc[mi][ni][r] + bv);
        }
      }
    __syncthreads();
#pragma unroll
    for (int rep = 0; rep < 8; ++rep) {
      int idx = rep * 4096 + tid * 8;      // u16 units; 32768 total
      int row = idx >> 7, col = idx & 127;
      *(u16x8*)(C + (m0 + row) * NCOLS + n0 + col) = *(const u16x8*)&sh[idx];
    }
  } else {
    float* C = (float*)Cv;
    float* shf = (float*)sh;               // 128 rows x 128 cols f32 = 64 KB
#pragma unroll
    for (int chunk = 0; chunk < 2; ++chunk) {
      __syncthreads();
      if ((wid >> 2) == chunk) {           // waves 0-3 rows 0-127; 4-7 rows 128-255
#pragma unroll
        for (int mi = 0; mi < 4; ++mi)
#pragma unroll
          for (int ni = 0; ni < 4; ++ni) {
            int col = wc + ni * 16 + c;
            float bv = bias[n0 + col];
#pragma unroll
            for (int r = 0; r < 4; ++r) {
              int lr = ((wid >> 1) & 1) * 64 + mi * 16 + g * 4 + r;  // 0..127
              shf[lr * 128 + col] = acc[mi][ni][r] + bv;
            }
          }
      }
      __syncthreads();
#pragma unroll
      for (int rep = 0; rep < 8; ++rep) {
        int idx = rep * 2048 + tid * 4;    // f32 units; 16384 total
        int row = idx >> 7, col = idx & 127;
        *(float4*)(C + (m0 + chunk * 128 + row) * NCOLS + n0 + col) =
            *(const float4*)&shf[idx];
      }
    }
  }
}

// ---------------- fused window attention: one wave per (b, h) ----------------
__global__ __launch_bounds__(256) void k_attn(const u16* __restrict__ qkv,
                                              const float* __restrict__ rpbm,
                                              u16* __restrict__ attnout) {
  __shared__ u16 P_lds[4][64 * 64];
  __shared__ u16 vT_lds[4][32 * 64];
  int lane = threadIdx.x & 63, wid = threadIdx.x >> 6;
  int blk = blockIdx.x;                  // 0..6143, w-major for rpbm L2 reuse
  int w = blk / 96;
  int rr = blk - w * 96;
  int j = rr / 3;
  int hb = rr - j * 3;
  int b = j * 64 + w;
  int h = hb * 4 + wid;
  const u16* base = qkv + (size_t)b * (NTOK * 1152);
  int c = lane & 15, g = lane >> 4;

  u16* vt = vT_lds[wid];
  {
    const u16* vbase = base + 2 * DIM + h * HD;
#pragma unroll
    for (int t = 0; t < 4; ++t) {
      int idx = t * 64 + lane;
      int jj = idx >> 2, d0 = (idx & 3) * 8;
      int jr = jj < NTOK ? jj : NTOK - 1;
      u16x8 vv = *(const u16x8*)(vbase + (size_t)jr * 1152 + d0);
#pragma unroll
      for (int dd = 0; dd < 8; ++dd) {
        int d = d0 + dd;
        int byte = (d * 128 + jj * 2) ^ ((d & 7) << 4);
        *(u16*)((char*)vt + byte) = (u16)vv[dd];
      }
    }
  }

  bf16x8 qa[4], kb[4];
#pragma unroll
  for (int mi = 0; mi < 4; ++mi) {
    int row = mi * 16 + c; if (row > NTOK - 1) row = NTOK - 1;
    qa[mi] = ld_bf8(base + (size_t)row * 1152 + h * HD + g * 8);
  }
#pragma unroll
  for (int ni = 0; ni < 4; ++ni) {
    int row = ni * 16 + c; if (row > NTOK - 1) row = NTOK - 1;
    kb[ni] = ld_bf8(base + (size_t)row * 1152 + DIM + h * HD + g * 8);
  }

  f32x4 s[4][4] = {};
#pragma unroll
  for (int mi = 0; mi < 4; ++mi)
#pragma unroll
    for (int ni = 0; ni < 4; ++ni)
      s[mi][ni] = __builtin_amdgcn_mfma_f32_16x16x32_bf16(qa[mi], kb[ni],
                                                          s[mi][ni], 0, 0, 0);

  const float scale = 0.17677669529663687f;   // 32^-0.5
  const f32x4* rp = (const f32x4*)(rpbm + ((size_t)(h * 64 + w)) * 4096);
#pragma unroll
  for (int mi = 0; mi < 4; ++mi)
#pragma unroll
    for (int ni = 0; ni < 4; ++ni) {
      f32x4 rv = rp[(mi * 4 + ni) * 64 + lane];
#pragma unroll
      for (int r = 0; r < 4; ++r)
        s[mi][ni][r] = s[mi][ni][r] * scale + rv[r];
    }

#pragma unroll
  for (int mi = 0; mi < 4; ++mi)
#pragma unroll
    for (int r = 0; r < 4; ++r) {
      float mx = fmaxf(fmaxf(s[mi][0][r], s[mi][1][r]),
                       fmaxf(s[mi][2][r], s[mi][3][r]));
      mx = fmaxf(mx, __shfl_xor(mx, 1));
      mx = fmaxf(mx, __shfl_xor(mx, 2));
      mx = fmaxf(mx, __shfl_xor(mx, 4));
      mx = fmaxf(mx, __shfl_xor(mx, 8));
      float sum = 0.f;
#pragma unroll
      for (int ni = 0; ni < 4; ++ni) {
        float p = __expf(s[mi][ni][r] - mx);
        s[mi][ni][r] = p;
        sum += p;
      }
      sum += __shfl_xor(sum, 1);
      sum += __shfl_xor(sum, 2);
      sum += __shfl_xor(sum, 4);
      sum += __shfl_xor(sum, 8);
      float inv = __builtin_amdgcn_rcpf(sum);
#pragma unroll
      for (int ni = 0; ni < 4; ++ni) s[mi][ni][r] *= inv;
    }

  u16* pl = P_lds[wid];
#pragma unroll
  for (int mi = 0; mi < 4; ++mi)
#pragma unroll
    for (int ni = 0; ni < 4; ++ni) {
      int col = ni * 16 + c;
#pragma unroll
      for (int r = 0; r < 4; ++r) {
        int row = mi * 16 + g * 4 + r;
        int byte = (row * 128 + col * 2) ^ ((row & 7) << 4);
        *(u16*)((char*)pl + byte) = f2b(s[mi][ni][r]);
      }
    }
  asm volatile("s_waitcnt lgkmcnt(0)" ::: "memory");

  f32x4 o[4][2] = {};
#pragma unroll
  for (int ks = 0; ks < 2; ++ks) {
    bf16x8 vb[2];
#pragma unroll
    for (int n2 = 0; n2 < 2; ++n2) {
      int d = n2 * 16 + c;
      int byte = (d * 128 + ks * 64 + g * 16) ^ ((d & 7) << 4);
      vb[n2] = __builtin_bit_cast(bf16x8, *(const u16x8*)((const char*)vt + byte));
    }
#pragma unroll
    for (int mi = 0; mi < 4; ++mi) {
      int row = mi * 16 + c;
      int byte = (row * 128 + ks * 64 + g * 16) ^ ((row & 7) << 4);
      bf16x8 pa = __builtin_bit_cast(bf16x8, *(const u16x8*)((const char*)pl + byte));
#pragma unroll
      for (int n2 = 0; n2 < 2; ++n2)
        o[mi][n2] = __builtin_amdgcn_mfma_f32_16x16x32_bf16(pa, vb[n2],
                                                            o[mi][n2], 0, 0, 0);
    }
  }

  u16* obase = attnout + (size_t)b * (NTOK * DIM) + h * HD;
#pragma unroll
  for (int mi = 0; mi < 4; ++mi)
#pragma unroll
    for (int r = 0; r < 4; ++r) {
      int row = mi * 16 + g * 4 + r;
      if (row < NTOK) {
#pragma unroll
        for (int n2 = 0; n2 < 2; ++n2)
          obase[(size_t)row * DIM + n2 * 16 + c] = f2b(o[mi][n2][r]);
      }
    }
}

// ---------------------------------------------------------------------------
extern "C" void kernel_launch(void* const* d_in, const int* in_sizes, int n_in,
                              void* d_out, int out_size, void* d_ws, size_t ws_size,
                              hipStream_t stream) {
  const float* x       = (const float*)d_in[0];
  const float* qkv_w   = (const float*)d_in[1];
  const float* qkv_b   = (const float*)d_in[2];
  const float* proj_w  = (const float*)d_in[3];
  const float* proj_b  = (const float*)d_in[4];
  const float* bias_tb = (const float*)d_in[5];
  const float* mask    = (const float*)d_in[6];
  const int*   rel_idx = (const int*)d_in[7];
  float* out = (float*)d_out;

  char* ws = (char*)d_ws;
  u16*   xb      = (u16*)(ws + 0);                  //  77,070,336  x bf16
  u16*   wqkvb   = (u16*)(ws + 77070336);           //     884,736  qkv_w bf16
  u16*   wprojb  = (u16*)(ws + 77955072);           //     294,912  proj_w bf16
  float* rpbm    = (float*)(ws + 78249984);         //  12,582,912  bias+mask
  u16*   qkv     = (u16*)(ws + 90832896);           // 231,211,008  qkv bf16
  u16*   attnout = (u16*)(ws + 322043904);          //  77,070,336  attn out bf16

  // 1) prep: all casts + fused bias+mask table
  k_prep<<<50496, 256, 0, stream>>>(x, xb, qkv_w, wqkvb, proj_w, wprojb,
                                    bias_tb, mask, rel_idx, rpbm);

  // 2) QKV GEMM (256x128, 8 waves): [100352,384] x [1152,384]^T -> bf16
  k_gemm256<1, 1152, 9, 441><<<3528, 512, 0, stream>>>(xb, wqkvb, qkv_b,
                                                       (void*)qkv);

  // 3) window attention -> bf16 [100352,384]
  k_attn<<<6144, 256, 0, stream>>>(qkv, rpbm, attnout);

  // 4) proj GEMM (256x128, 8 waves): [100352,384] x [384,384]^T -> f32 d_out
  k_gemm256<0, 384, 3, 147><<<1176, 512, 0, stream>>>(attnout, wprojb, proj_b,
                                                      (void*)out);

  (void)in_sizes; (void)n_in; (void)out_size; (void)ws_size;
}

// Round 12
// 341.725 us; speedup vs baseline: 1.0838x; 1.0016x over previous
//
#include <hip/hip_runtime.h>
#include <hip/hip_bf16.h>
#include <cstdint>
#include <cstddef>

// Problem constants
#define NTOK 49
#define DIM 384
#define KDIM 384
#define HEADS 12
#define HD 32
#define BATCH 2048
#define MROWS (BATCH * NTOK)   // 100352 = 392 * 256

typedef unsigned short u16;
typedef __bf16 bf16x8 __attribute__((ext_vector_type(8)));
typedef unsigned short u16x8 __attribute__((ext_vector_type(8)));
typedef float f32x4 __attribute__((ext_vector_type(4)));

__device__ __forceinline__ u16 f2b(float f) {
  union { float f; unsigned u; } v; v.f = f;
  unsigned r = v.u + 0x7fffu + ((v.u >> 16) & 1u);   // RNE bf16
  return (u16)(r >> 16);
}

__device__ __forceinline__ bf16x8 ld_bf8(const u16* p) {
  u16x8 u = *(const u16x8*)p;
  return __builtin_bit_cast(bf16x8, u);
}

__device__ __forceinline__ void gload_lds16(const void* g, void* l) {
  __builtin_amdgcn_global_load_lds(
      (const __attribute__((address_space(1))) unsigned*)g,
      (__attribute__((address_space(3))) unsigned*)l, 16, 0, 0);
}

// ---------------- prep: x/w casts + fused bias+mask table (TRANSPOSED) ------
// rpbmT layout matches S^T = K·Q^T fragments: frag row = k-token, col = q-token.
__global__ __launch_bounds__(256) void k_prep(const float* __restrict__ x,
                                              u16* __restrict__ xb,
                                              const float* __restrict__ qkv_w,
                                              u16* __restrict__ wqkvb,
                                              const float* __restrict__ proj_w,
                                              u16* __restrict__ wprojb,
                                              const float* __restrict__ bias_table,
                                              const float* __restrict__ mask,
                                              const int* __restrict__ rel_idx,
                                              float* __restrict__ rpbm) {
  int blk = blockIdx.x;
  if (blk < 38208) {
    const float* in;
    u16* out;
    int i;
    if (blk < 37632) {
      in = x; out = xb; i = blk * 256 + threadIdx.x;
    } else if (blk < 38064) {
      in = qkv_w; out = wqkvb; i = (blk - 37632) * 256 + threadIdx.x;
    } else {
      in = proj_w; out = wprojb; i = (blk - 38064) * 256 + threadIdx.x;
    }
    float4 v = ((const float4*)in)[i];
    ushort4 o;
    o.x = f2b(v.x); o.y = f2b(v.y); o.z = f2b(v.z); o.w = f2b(v.w);
    ((ushort4*)out)[i] = o;
  } else {
    int idx = (blk - 38208) * 256 + threadIdx.x;   // 12*64*4096 entries
    int r  = idx & 3;
    int l  = (idx >> 2) & 63;
    int ni = (idx >> 8) & 3;
    int mi = (idx >> 10) & 3;
    int w  = (idx >> 12) & 63;
    int h  = idx >> 18;
    int kk = mi * 16 + (l >> 4) * 4 + r;   // frag row = k-token
    int qq = ni * 16 + (l & 15);           // frag col = q-token
    float v = -1e30f;
    if (kk < NTOK && qq < NTOK)
      v = bias_table[rel_idx[qq * NTOK + kk] * HEADS + h] +
          mask[(w * NTOK + qq) * NTOK + kk];
    rpbm[idx] = v;
  }
}

// ------- NT GEMM: 256x128 tile, 512 thr / 8 waves, 3-buf counted vmcnt ------
template <int OUT_BF16, int NCOLS, int NTN, int GD8>
__global__ __launch_bounds__(512, 4) void k_gemm256(const u16* __restrict__ A,
                                                    const u16* __restrict__ B,
                                                    const float* __restrict__ bias,
                                                    void* __restrict__ Cv) {
  __shared__ u16 sh[36864];   // 72 KB: 3 x 24 KB; epilogue reuses 64 KB
  int bid = blockIdx.x;
  int tile = (bid & 7) * GD8 + (bid >> 3);   // XCD-contiguous (grid % 8 == 0)
  int mt = tile / NTN, nt = tile - mt * NTN;
  long m0 = (long)mt * 256;
  int n0 = nt * 128;
  int tid = threadIdx.x;
  int lane = tid & 63, wid = tid >> 6;           // 8 waves
  int wr = (wid >> 1) * 64, wc = (wid & 1) * 64; // 4M x 2N wave grid
  int c = lane & 15, g = lane >> 4;
  int gsw = (g ^ ((c >> 1) & 3)) * 8;            // swizzled read segment

  int srow = wid * 16 + (lane >> 2);             // 0..127
  int scol = ((lane & 3) ^ ((lane >> 3) & 3)) * 8;  // pre-swizzled global seg
  const u16* gA = A + (m0 + srow) * (long)KDIM + scol;
  const u16* gB = B + (long)(n0 + srow) * KDIM + scol;
  int lrow = srow, lseg = (lane & 3) * 8;        // linear LDS dest

  f32x4 acc[4][4] = {};
  bf16x8 af[4], bfr[4];

#define STAGE256(BUF, KT)                                                      \
  {                                                                            \
    u16* As_ = sh + (BUF) * 12288;                                             \
    u16* Bs_ = As_ + 8192;                                                     \
    gload_lds16(gA + (KT), &As_[lrow * 32 + lseg]);                            \
    gload_lds16(gA + (KT) + 128L * KDIM, &As_[(lrow + 128) * 32 + lseg]);      \
    gload_lds16(gB + (KT), &Bs_[lrow * 32 + lseg]);                            \
  }

#define FRAGREAD(BUF)                                                          \
  {                                                                            \
    const u16* As = sh + (BUF) * 12288;                                        \
    const u16* Bs = As + 8192;                                                 \
    _Pragma("unroll") for (int i = 0; i < 4; ++i) {                            \
      af[i]  = ld_bf8(&As[(wr + i * 16 + c) * 32 + gsw]);                      \
      bfr[i] = ld_bf8(&Bs[(wc + i * 16 + c) * 32 + gsw]);                      \
    }                                                                          \
  }

#define MFMA_CL                                                                \
  __builtin_amdgcn_s_setprio(1);                                               \
  _Pragma("unroll") for (int mi = 0; mi < 4; ++mi)                             \
  _Pragma("unroll") for (int ni = 0; ni < 4; ++ni)                             \
      acc[mi][ni] = __builtin_amdgcn_mfma_f32_16x16x32_bf16(                   \
          af[mi], bfr[ni], acc[mi][ni], 0, 0, 0);                              \
  __builtin_amdgcn_s_setprio(0);

#define GITER(T, NV)                                                           \
  {                                                                            \
    MFMA_CL;                                                                   \
    asm volatile("s_waitcnt vmcnt(" #NV ")" ::: "memory");                     \
    __builtin_amdgcn_s_barrier();                                              \
    __builtin_amdgcn_sched_barrier(0);                                         \
    if ((T) + 3 < 12) STAGE256((T) % 3, ((T) + 3) * 32);                       \
    FRAGREAD(((T) + 1) % 3);                                                   \
  }

  STAGE256(0, 0);
  STAGE256(1, 32);
  STAGE256(2, 64);
  asm volatile("s_waitcnt vmcnt(6)" ::: "memory");
  __builtin_amdgcn_s_barrier();
  __builtin_amdgcn_sched_barrier(0);
  FRAGREAD(0);

  GITER(0, 3)  GITER(1, 3)  GITER(2, 3)  GITER(3, 3)
  GITER(4, 3)  GITER(5, 3)  GITER(6, 3)  GITER(7, 3)
  GITER(8, 3)  GITER(9, 3)  GITER(10, 0)
  { MFMA_CL; }   // iter 11: pure MFMA
  __builtin_amdgcn_s_barrier();   // tile-11 reads retired before epilogue
#undef GITER
#undef MFMA_CL
#undef FRAGREAD
#undef STAGE256

  if (OUT_BF16) {
    u16* C = (u16*)Cv;
#pragma unroll
    for (int mi = 0; mi < 4; ++mi)
#pragma unroll
      for (int ni = 0; ni < 4; ++ni) {
        int col = wc + ni * 16 + c;
        float bv = bias[n0 + col];
#pragma unroll
        for (int r = 0; r < 4; ++r) {
          int row = wr + mi * 16 + g * 4 + r;       // 0..255
          sh[row * 128 + col] = f2b(acc[mi][ni][r] + bv);
        }
      }
    __syncthreads();
#pragma unroll
    for (int rep = 0; rep < 8; ++rep) {
      int idx = rep * 4096 + tid * 8;      // u16 units; 32768 total
      int row = idx >> 7, col = idx & 127;
      *(u16x8*)(C + (m0 + row) * NCOLS + n0 + col) = *(const u16x8*)&sh[idx];
    }
  } else {
    float* C = (float*)Cv;
    float* shf = (float*)sh;               // 128 rows x 128 cols f32 = 64 KB
#pragma unroll
    for (int chunk = 0; chunk < 2; ++chunk) {
      __syncthreads();
      if ((wid >> 2) == chunk) {
#pragma unroll
        for (int mi = 0; mi < 4; ++mi)
#pragma unroll
          for (int ni = 0; ni < 4; ++ni) {
            int col = wc + ni * 16 + c;
            float bv = bias[n0 + col];
#pragma unroll
            for (int r = 0; r < 4; ++r) {
              int lr = ((wid >> 1) & 1) * 64 + mi * 16 + g * 4 + r;
              shf[lr * 128 + col] = acc[mi][ni][r] + bv;
            }
          }
      }
      __syncthreads();
#pragma unroll
      for (int rep = 0; rep < 8; ++rep) {
        int idx = rep * 2048 + tid * 4;
        int row = idx >> 7, col = idx & 127;
        *(float4*)(C + (m0 + chunk * 128 + row) * NCOLS + n0 + col) =
            *(const float4*)&shf[idx];
      }
    }
  }
}

// -------- fused window attention, SWAPPED operands: one wave per (b, h) -----
// S^T = mfma(K, Q): lane's 4 acc entries are k-consecutive for a fixed q.
// Softmax over k = 16 lane-local values + shfl_xor(16,32).
// P packed via v_cvt_pk_bf16_f32 -> 16 ds_write_b64 (vs 64 scalar writes).
// PV: O^T = mfma(A=V^T, B=P[q][k] row-major b128 reads). Normalization
// deferred to the store (o * inv[q]).
__global__ __launch_bounds__(256) void k_attn(const u16* __restrict__ qkv,
                                              const float* __restrict__ rpbmT,
                                              u16* __restrict__ attnout) {
  __shared__ u16 P_lds[4][64 * 64];    // P[q][k] bf16, byte ^= (q&7)<<4
  __shared__ u16 vT_lds[4][32 * 64];
  int lane = threadIdx.x & 63, wid = threadIdx.x >> 6;
  int blk = blockIdx.x;                  // w-major remap for rpbmT L2 reuse
  int w = blk / 96;
  int rr = blk - w * 96;
  int j = rr / 3;
  int hb = rr - j * 3;
  int b = j * 64 + w;
  int h = hb * 4 + wid;
  const u16* base = qkv + (size_t)b * (NTOK * 1152);
  int c = lane & 15, g = lane >> 4;

  // ---- stage V transposed into LDS: vT[d][j], swizzled byte ^= (d&7)<<4 ----
  u16* vt = vT_lds[wid];
  {
    const u16* vbase = base + 2 * DIM + h * HD;
#pragma unroll
    for (int t = 0; t < 4; ++t) {
      int idx = t * 64 + lane;
      int jj = idx >> 2, d0 = (idx & 3) * 8;
      int jr = jj < NTOK ? jj : NTOK - 1;
      u16x8 vv = *(const u16x8*)(vbase + (size_t)jr * 1152 + d0);
#pragma unroll
      for (int dd = 0; dd < 8; ++dd) {
        int d = d0 + dd;
        int byte = (d * 128 + jj * 2) ^ ((d & 7) << 4);
        *(u16*)((char*)vt + byte) = (u16)vv[dd];
      }
    }
  }

  // ---- K fragments (A-role), Q fragments (B-role) ----
  bf16x8 kf[4], qf[4];
#pragma unroll
  for (int mi = 0; mi < 4; ++mi) {
    int row = mi * 16 + c; if (row > NTOK - 1) row = NTOK - 1;
    kf[mi] = ld_bf8(base + (size_t)row * 1152 + DIM + h * HD + g * 8);
  }
#pragma unroll
  for (int nj = 0; nj < 4; ++nj) {
    int row = nj * 16 + c; if (row > NTOK - 1) row = NTOK - 1;
    qf[nj] = ld_bf8(base + (size_t)row * 1152 + h * HD + g * 8);
  }

  // ---- S^T[k][q] = K Q^T ----
  f32x4 s[4][4];
  f32x4 zf = {0.f, 0.f, 0.f, 0.f};
#pragma unroll
  for (int mi = 0; mi < 4; ++mi)
#pragma unroll
    for (int nj = 0; nj < 4; ++nj)
      s[mi][nj] = __builtin_amdgcn_mfma_f32_16x16x32_bf16(kf[mi], qf[nj], zf,
                                                          0, 0, 0);

  // ---- scale + transposed bias+mask table ----
  const float scale = 0.17677669529663687f;   // 32^-0.5
  const f32x4* rp = (const f32x4*)(rpbmT + ((size_t)(h * 64 + w)) * 4096);
#pragma unroll
  for (int mi = 0; mi < 4; ++mi)
#pragma unroll
    for (int nj = 0; nj < 4; ++nj) {
      f32x4 rv = rp[(mi * 4 + nj) * 64 + lane];
#pragma unroll
      for (int r = 0; r < 4; ++r)
        s[mi][nj][r] = s[mi][nj][r] * scale + rv[r];
    }

  // ---- softmax over k (per q-column): 16 lane-local + 2 shfls ----
  float inv[4];
#pragma unroll
  for (int nj = 0; nj < 4; ++nj) {
    float mx = s[0][nj][0];
#pragma unroll
    for (int mi = 0; mi < 4; ++mi)
#pragma unroll
      for (int r = 0; r < 4; ++r)
        mx = fmaxf(mx, s[mi][nj][r]);
    mx = fmaxf(mx, __shfl_xor(mx, 16));
    mx = fmaxf(mx, __shfl_xor(mx, 32));
    float sum = 0.f;
#pragma unroll
    for (int mi = 0; mi < 4; ++mi)
#pragma unroll
      for (int r = 0; r < 4; ++r) {
        float p = __expf(s[mi][nj][r] - mx);
        s[mi][nj][r] = p;
        sum += p;
      }
    sum += __shfl_xor(sum, 16);
    sum += __shfl_xor(sum, 32);
    inv[nj] = __builtin_amdgcn_rcpf(sum);
  }

  // ---- P[q][k] -> LDS: cvt_pk pairs, 16 x ds_write_b64, swizzled ----
  u16* pl = P_lds[wid];
#pragma unroll
  for (int mi = 0; mi < 4; ++mi)
#pragma unroll
    for (int nj = 0; nj < 4; ++nj) {
      unsigned w0, w1;
      asm("v_cvt_pk_bf16_f32 %0, %1, %2"
          : "=v"(w0) : "v"(s[mi][nj][0]), "v"(s[mi][nj][1]));
      asm("v_cvt_pk_bf16_f32 %0, %1, %2"
          : "=v"(w1) : "v"(s[mi][nj][2]), "v"(s[mi][nj][3]));
      int q = nj * 16 + c;
      int byte = (q * 128 + (mi * 16 + g * 4) * 2) ^ ((c & 7) << 4);
      uint2 val; val.x = w0; val.y = w1;
      *(uint2*)((char*)pl + byte) = val;
    }
  asm volatile("s_waitcnt lgkmcnt(0)" ::: "memory");
  __builtin_amdgcn_sched_barrier(0);

  // ---- O^T[d][q] = V^T P^T : A = vT (verified path), B = P rows (b128) ----
  f32x4 o[2][4] = {};
#pragma unroll
  for (int ks = 0; ks < 2; ++ks) {
    bf16x8 vb[2];
#pragma unroll
    for (int mi2 = 0; mi2 < 2; ++mi2) {
      int d = mi2 * 16 + c;
      int byte = (d * 128 + ks * 64 + g * 16) ^ ((d & 7) << 4);
      vb[mi2] = __builtin_bit_cast(bf16x8, *(const u16x8*)((const char*)vt + byte));
    }
#pragma unroll
    for (int nj = 0; nj < 4; ++nj) {
      int q = nj * 16 + c;
      int byte = (q * 128 + (ks * 32 + g * 8) * 2) ^ ((c & 7) << 4);
      bf16x8 pb = __builtin_bit_cast(bf16x8, *(const u16x8*)((const char*)pl + byte));
#pragma unroll
      for (int mi2 = 0; mi2 < 2; ++mi2)
        o[mi2][nj] = __builtin_amdgcn_mfma_f32_16x16x32_bf16(vb[mi2], pb,
                                                             o[mi2][nj], 0, 0, 0);
    }
  }

  // ---- store O[b, q, h*32 + d] = o * inv[q] (deferred normalization) ----
  u16* obase = attnout + (size_t)b * (NTOK * DIM) + h * HD;
#pragma unroll
  for (int mi2 = 0; mi2 < 2; ++mi2)
#pragma unroll
    for (int nj = 0; nj < 4; ++nj) {
      int q = nj * 16 + c;
      if (q < NTOK) {
#pragma unroll
        for (int r = 0; r < 4; ++r)
          obase[(size_t)q * DIM + mi2 * 16 + g * 4 + r] =
              f2b(o[mi2][nj][r] * inv[nj]);
      }
    }
}

// ---------------------------------------------------------------------------
extern "C" void kernel_launch(void* const* d_in, const int* in_sizes, int n_in,
                              void* d_out, int out_size, void* d_ws, size_t ws_size,
                              hipStream_t stream) {
  const float* x       = (const float*)d_in[0];
  const float* qkv_w   = (const float*)d_in[1];
  const float* qkv_b   = (const float*)d_in[2];
  const float* proj_w  = (const float*)d_in[3];
  const float* proj_b  = (const float*)d_in[4];
  const float* bias_tb = (const float*)d_in[5];
  const float* mask    = (const float*)d_in[6];
  const int*   rel_idx = (const int*)d_in[7];
  float* out = (float*)d_out;

  char* ws = (char*)d_ws;
  u16*   xb      = (u16*)(ws + 0);                  //  77,070,336  x bf16
  u16*   wqkvb   = (u16*)(ws + 77070336);           //     884,736  qkv_w bf16
  u16*   wprojb  = (u16*)(ws + 77955072);           //     294,912  proj_w bf16
  float* rpbm    = (float*)(ws + 78249984);         //  12,582,912  bias+mask^T
  u16*   qkv     = (u16*)(ws + 90832896);           // 231,211,008  qkv bf16
  u16*   attnout = (u16*)(ws + 322043904);          //  77,070,336  attn out bf16

  // 1) prep: all casts + transposed bias+mask table
  k_prep<<<50496, 256, 0, stream>>>(x, xb, qkv_w, wqkvb, proj_w, wprojb,
                                    bias_tb, mask, rel_idx, rpbm);

  // 2) QKV GEMM (256x128, 8 waves): [100352,384] x [1152,384]^T -> bf16
  k_gemm256<1, 1152, 9, 441><<<3528, 512, 0, stream>>>(xb, wqkvb, qkv_b,
                                                       (void*)qkv);

  // 3) window attention (swapped-operand) -> bf16 [100352,384]
  k_attn<<<6144, 256, 0, stream>>>(qkv, rpbm, attnout);

  // 4) proj GEMM (256x128, 8 waves): [100352,384] x [384,384]^T -> f32 d_out
  k_gemm256<0, 384, 3, 147><<<1176, 512, 0, stream>>>(attnout, wprojb, proj_b,
                                                      (void*)out);

  (void)in_sizes; (void)n_in; (void)out_size; (void)ws_size;
}